// Round 1
// baseline (377.249 us; speedup 1.0000x reference)
//
#include <hip/hip_runtime.h>

// Problem constants (from reference): B=8, C=64, H=256, W=512, 3x3 taps, O=1,
// output upsampled 2x2 -> (8, 1, 512, 1024) fp32.
#define Bn   8
#define Cn   64
#define Hn   256
#define Wn   512
#define HWn  (Hn * Wn)
#define TAPS 9

// ---------------------------------------------------------------------------
// Pass 1: channel-dot. D[k][b][y][x] = sum_c feature[b][c][y][x] * w[c][k].
// Each thread handles 4 consecutive x via float4 (fully coalesced stream of
// the 256 MB feature tensor, read exactly once).
// Weights are wave-uniform -> compiler emits scalar loads (s_load).
// ---------------------------------------------------------------------------
__global__ __launch_bounds__(256) void pass1_chandot(
    const float* __restrict__ feat, const float* __restrict__ wt,
    float* __restrict__ D)
{
    int t   = blockIdx.x * blockDim.x + threadIdx.x;  // B*H*W/4 threads
    int x   = (t & (Wn / 4 - 1)) << 2;                // 0..508 step 4
    int row = t >> 7;                                 // b*H + y
    int b   = row >> 8;
    int y   = row & (Hn - 1);

    size_t fbase = (size_t)b * Cn * HWn + (size_t)y * Wn + x;

    float4 acc[TAPS];
#pragma unroll
    for (int k = 0; k < TAPS; ++k) acc[k] = make_float4(0.f, 0.f, 0.f, 0.f);

#pragma unroll 4
    for (int c = 0; c < Cn; ++c) {
        float4 f = *(const float4*)(feat + fbase + (size_t)c * HWn);
#pragma unroll
        for (int k = 0; k < TAPS; ++k) {
            float wv = wt[c * TAPS + k];
            acc[k].x = fmaf(f.x, wv, acc[k].x);
            acc[k].y = fmaf(f.y, wv, acc[k].y);
            acc[k].z = fmaf(f.z, wv, acc[k].z);
            acc[k].w = fmaf(f.w, wv, acc[k].w);
        }
    }

    size_t dbase = (size_t)b * HWn + (size_t)y * Wn + x;
#pragma unroll
    for (int k = 0; k < TAPS; ++k)
        *(float4*)(D + (size_t)k * (Bn * HWn) + dbase) = acc[k];
}

// ---------------------------------------------------------------------------
// Pass 2: gather 9 taps from D, sum, write the 2x2 upsampled output.
// gj is near-monotonic in w, so lanes (consecutive w) read near-consecutive
// addresses of the k-th D plane -> good coalescing; D is L2/L3 resident.
// ---------------------------------------------------------------------------
__global__ __launch_bounds__(256) void pass2_gather(
    const float* __restrict__ D, const int* __restrict__ gi,
    const int* __restrict__ gj, float* __restrict__ out)
{
    int p = blockIdx.x * blockDim.x + threadIdx.x;    // B*H*W threads
    int w = p & (Wn - 1);
    int h = (p >> 9) & (Hn - 1);
    int b = p >> 17;

    int iidx = ((h << 9) | w) * TAPS;                 // [H][W][9] int32

    float acc = 0.f;
#pragma unroll
    for (int k = 0; k < TAPS; ++k) {
        int yi = gi[iidx + k];
        int xj = gj[iidx + k];
        acc += D[(size_t)k * (Bn * HWn) + (size_t)b * HWn + yi * Wn + xj];
    }

    float2 v = make_float2(acc, acc);
    size_t o0 = ((size_t)b * (2 * Hn) + 2 * h) * (size_t)(2 * Wn) + 2 * w;
    *(float2*)(out + o0)            = v;   // rows 2h and 2h+1, cols 2w,2w+1
    *(float2*)(out + o0 + 2 * Wn)   = v;
}

// ---------------------------------------------------------------------------
// Fallback (only if ws_size < 37.7 MB): direct per-pixel 9x64 gather-dot.
// Correct but ~9x more load traffic than the two-pass path.
// ---------------------------------------------------------------------------
__global__ __launch_bounds__(256) void direct_kernel(
    const float* __restrict__ feat, const float* __restrict__ wt,
    const int* __restrict__ gi, const int* __restrict__ gj,
    float* __restrict__ out)
{
    int p = blockIdx.x * blockDim.x + threadIdx.x;
    int w = p & (Wn - 1);
    int h = (p >> 9) & (Hn - 1);
    int b = p >> 17;

    int iidx = ((h << 9) | w) * TAPS;
    int off[TAPS];
#pragma unroll
    for (int k = 0; k < TAPS; ++k)
        off[k] = gi[iidx + k] * Wn + gj[iidx + k];

    float acc = 0.f;
    for (int c = 0; c < Cn; ++c) {
        const float* fc = feat + ((size_t)b * Cn + c) * HWn;
#pragma unroll
        for (int k = 0; k < TAPS; ++k)
            acc = fmaf(fc[off[k]], wt[c * TAPS + k], acc);
    }

    float2 v = make_float2(acc, acc);
    size_t o0 = ((size_t)b * (2 * Hn) + 2 * h) * (size_t)(2 * Wn) + 2 * w;
    *(float2*)(out + o0)          = v;
    *(float2*)(out + o0 + 2 * Wn) = v;
}

extern "C" void kernel_launch(void* const* d_in, const int* in_sizes, int n_in,
                              void* d_out, int out_size, void* d_ws, size_t ws_size,
                              hipStream_t stream) {
    const float* feat = (const float*)d_in[0];   // [8,64,256,512] fp32
    const float* wt   = (const float*)d_in[1];   // [1,64,3,3]     fp32
    const int*   gi   = (const int*)d_in[2];     // [256,512,9]    int32
    const int*   gj   = (const int*)d_in[3];     // [256,512,9]    int32
    float*       out  = (float*)d_out;           // [8,1,512,1024] fp32

    const size_t needD = (size_t)TAPS * Bn * HWn * sizeof(float);  // 37.7 MB

    if (ws_size >= needD) {
        float* D = (float*)d_ws;
        pass1_chandot<<<(Bn * HWn / 4) / 256, 256, 0, stream>>>(feat, wt, D);
        pass2_gather <<<(Bn * HWn) / 256,     256, 0, stream>>>(D, gi, gj, out);
    } else {
        direct_kernel<<<(Bn * HWn) / 256, 256, 0, stream>>>(feat, wt, gi, gj, out);
    }
}